// Round 1
// baseline (3168.173 us; speedup 1.0000x reference)
//
#include <hip/hip_runtime.h>
#include <cstdint>

#define BT 4096
#define HD 2048
#define VD 32000

typedef __attribute__((ext_vector_type(4))) float float4_t;
typedef __attribute__((ext_vector_type(4))) short short4_t;
typedef __attribute__((ext_vector_type(8))) short short8_t;

constexpr int BM = 128, BN = 128, BK = 32;

// f32 -> bf16 round-to-nearest-even (inputs are normal, no NaN handling needed)
__device__ __forceinline__ unsigned short f2bf(float f) {
  unsigned u = __float_as_uint(f);
  u += 0x7FFFu + ((u >> 16) & 1u);
  return (unsigned short)(u >> 16);
}

__device__ __forceinline__ short8_t pack8(float4_t a, float4_t b) {
  short8_t h;
  h[0] = (short)f2bf(a.x); h[1] = (short)f2bf(a.y);
  h[2] = (short)f2bf(a.z); h[3] = (short)f2bf(a.w);
  h[4] = (short)f2bf(b.x); h[5] = (short)f2bf(b.y);
  h[6] = (short)f2bf(b.z); h[7] = (short)f2bf(b.w);
  return h;
}

// async global->LDS, 16B per lane; LDS dest is wave-uniform base + lane*16.
// Generic->AS casts go through uintptr_t (LDS aperture is 4GB-aligned, low 32
// bits of a generic LDS pointer are the AS(3) offset -- CK's pattern).
__device__ __forceinline__ void async_copy16(const void* g, void* l) {
  __builtin_amdgcn_global_load_lds(
      (__attribute__((address_space(1))) void*)(uintptr_t)(g),
      (__attribute__((address_space(3))) void*)(uint32_t)(uintptr_t)(l),
      16, 0, 0);
}

__global__ __launch_bounds__(256) void cast_f32_to_bf16(
    const float4_t* __restrict__ in, short4_t* __restrict__ out, int n4) {
  for (int i = blockIdx.x * 256 + threadIdx.x; i < n4; i += gridDim.x * 256) {
    float4_t v = in[i];
    short4_t o;
    o.x = (short)f2bf(v.x); o.y = (short)f2bf(v.y);
    o.z = (short)f2bf(v.z); o.w = (short)f2bf(v.w);
    out[i] = o;
  }
}

// One 128x128 C-tile accumulated over K (m97 structure).
// A: [M x K] rows at m0..m0+127, B: [N x K] rows at n0..n0+127 (B^T form; W is V x H).
template <bool F32SRC>
__device__ __forceinline__ void ktile(const void* A, const void* B,
                                      float4_t (&acc)[4][4],
                                      unsigned short* As, unsigned short* Bs,
                                      int m0, int n0) {
  const int tid = threadIdx.x;
  const int lane = tid & 63;
  const int wave = tid >> 6;
  const int wm = wave >> 1, wn = wave & 1;
  const int r0 = tid >> 2, c0 = tid & 3;  // chunk = row*4 + c, 16B chunks
  const int row16 = lane & 15, kq = lane >> 4;
  const int aoff = (wm * 64 + row16) * BK + kq * 8;
  const int boff = (wn * 64 + row16) * BK + kq * 8;
  const int lds0 = __builtin_amdgcn_readfirstlane(wave * 1024);
  const int lds1 = __builtin_amdgcn_readfirstlane(4096 + wave * 1024);

  const unsigned short* Ab = nullptr; const unsigned short* Bb = nullptr;
  const float* Af = nullptr; const float* Bf = nullptr;
  if constexpr (!F32SRC) {
    Ab = (const unsigned short*)A + (size_t)(m0 + r0) * HD + c0 * 8;
    Bb = (const unsigned short*)B + (size_t)(n0 + r0) * HD + c0 * 8;
  } else {
    Af = (const float*)A + (size_t)(m0 + r0) * HD + c0 * 8;
    Bf = (const float*)B + (size_t)(n0 + r0) * HD + c0 * 8;
  }

  for (int kb = 0; kb < HD / BK; ++kb) {
    const int ke = kb * BK;
    if constexpr (!F32SRC) {
      async_copy16(Ab + ke, (char*)As + lds0);
      async_copy16(Ab + (size_t)64 * HD + ke, (char*)As + lds1);
      async_copy16(Bb + ke, (char*)Bs + lds0);
      async_copy16(Bb + (size_t)64 * HD + ke, (char*)Bs + lds1);
    } else {
      short8_t hA0 = pack8(*(const float4_t*)(Af + ke), *(const float4_t*)(Af + ke + 4));
      short8_t hA1 = pack8(*(const float4_t*)(Af + (size_t)64 * HD + ke),
                           *(const float4_t*)(Af + (size_t)64 * HD + ke + 4));
      short8_t hB0 = pack8(*(const float4_t*)(Bf + ke), *(const float4_t*)(Bf + ke + 4));
      short8_t hB1 = pack8(*(const float4_t*)(Bf + (size_t)64 * HD + ke),
                           *(const float4_t*)(Bf + (size_t)64 * HD + ke + 4));
      *(short8_t*)((char*)As + tid * 16) = hA0;
      *(short8_t*)((char*)As + 4096 + tid * 16) = hA1;
      *(short8_t*)((char*)Bs + tid * 16) = hB0;
      *(short8_t*)((char*)Bs + 4096 + tid * 16) = hB1;
    }
    __syncthreads();
    short8_t af[4], bf[4];
#pragma unroll
    for (int mi = 0; mi < 4; ++mi) af[mi] = *(const short8_t*)(As + aoff + mi * 16 * BK);
#pragma unroll
    for (int ni = 0; ni < 4; ++ni) bf[ni] = *(const short8_t*)(Bs + boff + ni * 16 * BK);
#pragma unroll
    for (int mi = 0; mi < 4; ++mi)
#pragma unroll
      for (int ni = 0; ni < 4; ++ni)
        acc[mi][ni] = __builtin_amdgcn_mfma_f32_16x16x32_bf16(af[mi], bf[ni], acc[mi][ni], 0, 0, 0);
    __syncthreads();
  }
}

// Pass 1: GEMM; optionally store f32 logits; always accumulate per-row sum(exp(z)).
// grid: (M/BM, V/BN, 2) -- z selects (student, teacher); x = m-tile (fastest) so X stays in LLC.
template <bool F32SRC, bool STORE>
__global__ __launch_bounds__(256, 2) void gemm_pass1(
    const void* A0, const void* A1, const void* B0, const void* B1,
    float* __restrict__ rowsum, float* __restrict__ store) {
  __shared__ __align__(16) unsigned short As[BM * BK];
  __shared__ __align__(16) unsigned short Bs[BN * BK];
  const int m0 = blockIdx.x * BM;
  const int n0 = blockIdx.y * BN;
  const int z = blockIdx.z;
  const void* A = z ? A1 : A0;
  const void* B = z ? B1 : B0;
  float4_t acc[4][4] = {};
  ktile<F32SRC>(A, B, acc, As, Bs, m0, n0);

  const int tid = threadIdx.x;
  const int lane = tid & 63;
  const int wave = tid >> 6;
  const int wm = wave >> 1, wn = wave & 1;
  const int row16 = lane & 15, kq = lane >> 4;

  if constexpr (STORE) {
    float* st = store + (size_t)z * BT * VD;
#pragma unroll
    for (int mi = 0; mi < 4; ++mi)
#pragma unroll
      for (int r = 0; r < 4; ++r) {
        const size_t grow = (size_t)(m0 + wm * 64 + mi * 16 + kq * 4 + r);
        const size_t gc0 = (size_t)(n0 + wn * 64 + row16);
#pragma unroll
        for (int ni = 0; ni < 4; ++ni) st[grow * VD + gc0 + ni * 16] = acc[mi][ni][r];
      }
  }

  float* rs = rowsum + z * BT;
#pragma unroll
  for (int mi = 0; mi < 4; ++mi)
#pragma unroll
    for (int r = 0; r < 4; ++r) {
      float s = __expf(acc[mi][0][r]) + __expf(acc[mi][1][r]) +
                __expf(acc[mi][2][r]) + __expf(acc[mi][3][r]);
      s += __shfl_xor(s, 1);
      s += __shfl_xor(s, 2);
      s += __shfl_xor(s, 4);
      s += __shfl_xor(s, 8);
      if (row16 == 0) atomicAdd(&rs[m0 + wm * 64 + mi * 16 + kq * 4 + r], s);
    }
}

// stats[i] = log(sum_exp) -> LSE; thread 0 seeds out with +ln2 (plain store,
// runs before any pass-2 atomics on the same stream).
__global__ __launch_bounds__(256) void lse_fix(float* __restrict__ stats,
                                               float* __restrict__ out) {
  const int i = blockIdx.x * 256 + threadIdx.x;
  if (i < 2 * BT) stats[i] = __logf(stats[i]);
  if (i == 0) out[0] = 0.6931471805599453f;
}

// Pass 2 (materialized path): elementwise JSD terms from stored logits.
__global__ __launch_bounds__(256) void loss_from_logits(
    const float4_t* __restrict__ zs, const float4_t* __restrict__ zt,
    const float* __restrict__ lse, float* __restrict__ out) {
  const long long n4 = (long long)BT * VD / 4;
  float local = 0.f;
  for (long long i = (long long)blockIdx.x * 256 + threadIdx.x; i < n4;
       i += (long long)gridDim.x * 256) {
    const int row = (int)(i / (VD / 4));
    const float es = lse[row], et = lse[BT + row];
    const float4_t a = zs[i], b = zt[i];
#pragma unroll
    for (int c = 0; c < 4; ++c) {
      const float ls = a[c] - es, lt = b[c] - et;
      const float p = __expf(ls), q = __expf(lt);
      local += p * ls + q * lt - (p + q) * __logf(p + q);
    }
  }
  local += __shfl_xor(local, 1);
  local += __shfl_xor(local, 2);
  local += __shfl_xor(local, 4);
  local += __shfl_xor(local, 8);
  local += __shfl_xor(local, 16);
  local += __shfl_xor(local, 32);
  __shared__ float red[4];
  const int lane = threadIdx.x & 63, wave = threadIdx.x >> 6;
  if (lane == 0) red[wave] = local;
  __syncthreads();
  if (threadIdx.x == 0)
    atomicAdd(out, (red[0] + red[1] + red[2] + red[3]) * (0.5f / BT));
}

// Pass 2 (recompute path): both GEMM tiles (student+teacher) then joint JSD terms.
template <bool F32SRC>
__global__ __launch_bounds__(256, 2) void gemm_loss(
    const void* Asg, const void* Bsg, const void* Atg, const void* Btg,
    const float* __restrict__ lse, float* __restrict__ out) {
  __shared__ __align__(16) unsigned short As[BM * BK];
  __shared__ __align__(16) unsigned short Bs[BN * BK];
  __shared__ float red[4];
  const int m0 = blockIdx.x * BM;
  const int n0 = blockIdx.y * BN;
  float4_t acc_s[4][4] = {};
  ktile<F32SRC>(Asg, Bsg, acc_s, As, Bs, m0, n0);
  float4_t acc_t[4][4] = {};
  ktile<F32SRC>(Atg, Btg, acc_t, As, Bs, m0, n0);

  const int tid = threadIdx.x;
  const int lane = tid & 63;
  const int wave = tid >> 6;
  const int wm = wave >> 1;
  const int kq = lane >> 4;

  float local = 0.f;
#pragma unroll
  for (int mi = 0; mi < 4; ++mi)
#pragma unroll
    for (int r = 0; r < 4; ++r) {
      const int grow = m0 + wm * 64 + mi * 16 + kq * 4 + r;
      const float es = lse[grow], et = lse[BT + grow];
#pragma unroll
      for (int ni = 0; ni < 4; ++ni) {
        const float ls = acc_s[mi][ni][r] - es;
        const float lt = acc_t[mi][ni][r] - et;
        const float p = __expf(ls), q = __expf(lt);
        local += p * ls + q * lt - (p + q) * __logf(p + q);
      }
    }
  local += __shfl_xor(local, 1);
  local += __shfl_xor(local, 2);
  local += __shfl_xor(local, 4);
  local += __shfl_xor(local, 8);
  local += __shfl_xor(local, 16);
  local += __shfl_xor(local, 32);
  if (lane == 0) red[wave] = local;
  __syncthreads();
  if (tid == 0) atomicAdd(out, (red[0] + red[1] + red[2] + red[3]) * (0.5f / BT));
}

extern "C" void kernel_launch(void* const* d_in, const int* in_sizes, int n_in,
                              void* d_out, int out_size, void* d_ws, size_t ws_size,
                              hipStream_t stream) {
  const float* Xs = (const float*)d_in[0];
  const float* Xt = (const float*)d_in[1];
  const float* Ws = (const float*)d_in[2];
  const float* Wt = (const float*)d_in[3];
  float* out = (float*)d_out;
  char* ws = (char*)d_ws;

  const size_t STATS_B = (size_t)2 * BT * sizeof(float);          // 32 KB
  const size_t XB = (size_t)BT * HD * 2;                          // bf16 X
  const size_t WB = (size_t)VD * HD * 2;                          // bf16 W
  const size_t LOGIT_B = (size_t)BT * VD * 4;                     // f32 logits
  const size_t PRECAST_NEED = STATS_B + 2 * XB + 2 * WB;          // ~296 MB
  const size_t FULL_NEED = PRECAST_NEED + 2 * LOGIT_B;            // ~1.34 GB
  const size_t MID_NEED = STATS_B + 2 * LOGIT_B;                  // ~1.05 GB

  float* stats = (float*)ws;
  hipMemsetAsync(stats, 0, STATS_B, stream);

  const dim3 blk(256);
  const dim3 g1(BT / BM, VD / BN, 2);
  const dim3 g2(BT / BM, VD / BN, 1);
  const int XN4 = BT * HD / 4;
  const int WN4 = VD * HD / 4;

  if (ws_size >= FULL_NEED) {
    // precast bf16 + materialize logits (GEMM runs once, best path)
    unsigned short* bXs = (unsigned short*)(ws + STATS_B);
    unsigned short* bXt = bXs + (size_t)BT * HD;
    unsigned short* bWs = bXt + (size_t)BT * HD;
    unsigned short* bWt = bWs + (size_t)VD * HD;
    float* logits = (float*)(ws + PRECAST_NEED);
    cast_f32_to_bf16<<<dim3(512), blk, 0, stream>>>((const float4_t*)Xs, (short4_t*)bXs, XN4);
    cast_f32_to_bf16<<<dim3(512), blk, 0, stream>>>((const float4_t*)Xt, (short4_t*)bXt, XN4);
    cast_f32_to_bf16<<<dim3(2048), blk, 0, stream>>>((const float4_t*)Ws, (short4_t*)bWs, WN4);
    cast_f32_to_bf16<<<dim3(2048), blk, 0, stream>>>((const float4_t*)Wt, (short4_t*)bWt, WN4);
    gemm_pass1<false, true><<<g1, blk, 0, stream>>>(bXs, bXt, bWs, bWt, stats, logits);
    lse_fix<<<dim3(32), blk, 0, stream>>>(stats, out);
    loss_from_logits<<<dim3(4096), blk, 0, stream>>>(
        (const float4_t*)logits, (const float4_t*)(logits + (size_t)BT * VD), stats, out);
  } else if (ws_size >= MID_NEED) {
    // materialize logits, stage f32->bf16 on the fly
    float* logits = (float*)(ws + STATS_B);
    gemm_pass1<true, true><<<g1, blk, 0, stream>>>(Xs, Xt, Ws, Wt, stats, logits);
    lse_fix<<<dim3(32), blk, 0, stream>>>(stats, out);
    loss_from_logits<<<dim3(4096), blk, 0, stream>>>(
        (const float4_t*)logits, (const float4_t*)(logits + (size_t)BT * VD), stats, out);
  } else if (ws_size >= PRECAST_NEED) {
    // precast bf16, recompute logits in pass 2
    unsigned short* bXs = (unsigned short*)(ws + STATS_B);
    unsigned short* bXt = bXs + (size_t)BT * HD;
    unsigned short* bWs = bXt + (size_t)BT * HD;
    unsigned short* bWt = bWs + (size_t)VD * HD;
    cast_f32_to_bf16<<<dim3(512), blk, 0, stream>>>((const float4_t*)Xs, (short4_t*)bXs, XN4);
    cast_f32_to_bf16<<<dim3(512), blk, 0, stream>>>((const float4_t*)Xt, (short4_t*)bXt, XN4);
    cast_f32_to_bf16<<<dim3(2048), blk, 0, stream>>>((const float4_t*)Ws, (short4_t*)bWs, WN4);
    cast_f32_to_bf16<<<dim3(2048), blk, 0, stream>>>((const float4_t*)Wt, (short4_t*)bWt, WN4);
    gemm_pass1<false, false><<<g1, blk, 0, stream>>>(bXs, bXt, bWs, bWt, stats, nullptr);
    lse_fix<<<dim3(32), blk, 0, stream>>>(stats, out);
    gemm_loss<false><<<g2, blk, 0, stream>>>(bXs, bWs, bXt, bWt, stats, out);
  } else {
    // minimal-ws fallback: everything on the fly (needs only 32 KB)
    gemm_pass1<true, false><<<g1, blk, 0, stream>>>(Xs, Xt, Ws, Wt, stats, nullptr);
    lse_fix<<<dim3(32), blk, 0, stream>>>(stats, out);
    gemm_loss<true><<<g2, blk, 0, stream>>>(Xs, Ws, Xt, Wt, stats, out);
  }
  (void)in_sizes; (void)n_in; (void)out_size;
}

// Round 2
// 2003.324 us; speedup vs baseline: 1.5815x; 1.5815x over previous
//
#include <hip/hip_runtime.h>
#include <cstdint>

#define BT 4096
#define HD 2048
#define VD 32000

typedef __attribute__((ext_vector_type(4))) float float4_t;
typedef __attribute__((ext_vector_type(4))) short short4_t;
typedef __attribute__((ext_vector_type(8))) short short8_t;
typedef __attribute__((ext_vector_type(8))) unsigned short ushort8_t;

constexpr int BM = 128, BN = 128, BK = 32;

// f32 -> bf16 round-to-nearest-even (inputs are normal, no NaN handling needed)
__device__ __forceinline__ unsigned short f2bf(float f) {
  unsigned u = __float_as_uint(f);
  u += 0x7FFFu + ((u >> 16) & 1u);
  return (unsigned short)(u >> 16);
}

__device__ __forceinline__ float bf2f(unsigned short h) {
  return __uint_as_float((unsigned)h << 16);
}

__device__ __forceinline__ short8_t pack8(float4_t a, float4_t b) {
  short8_t h;
  h[0] = (short)f2bf(a.x); h[1] = (short)f2bf(a.y);
  h[2] = (short)f2bf(a.z); h[3] = (short)f2bf(a.w);
  h[4] = (short)f2bf(b.x); h[5] = (short)f2bf(b.y);
  h[6] = (short)f2bf(b.z); h[7] = (short)f2bf(b.w);
  return h;
}

// async global->LDS, 16B per lane; LDS dest is wave-uniform base + lane*16.
__device__ __forceinline__ void async_copy16(const void* g, void* l) {
  __builtin_amdgcn_global_load_lds(
      (__attribute__((address_space(1))) void*)(uintptr_t)(g),
      (__attribute__((address_space(3))) void*)(uint32_t)(uintptr_t)(l),
      16, 0, 0);
}

__global__ __launch_bounds__(256) void cast_f32_to_bf16(
    const float4_t* __restrict__ in, short4_t* __restrict__ out, int n4) {
  for (int i = blockIdx.x * 256 + threadIdx.x; i < n4; i += gridDim.x * 256) {
    float4_t v = in[i];
    short4_t o;
    o.x = (short)f2bf(v.x); o.y = (short)f2bf(v.y);
    o.z = (short)f2bf(v.z); o.w = (short)f2bf(v.w);
    out[i] = o;
  }
}

// LDS bank-conflict swizzle: chunk-slot XOR key per row. Rows stride 64 B
// (half of the 128 B bank span); key (row^row>>2)&3 spreads each 8-lane
// service group across all 8 four-bank groups. Depends only on row mod 16,
// so fragment reads at row16 + 16*mi + 64*wm share one key.
__device__ __forceinline__ int swz(int row) { return (row ^ (row >> 2)) & 3; }

// One 128x128 C-tile accumulated over K (m97 structure + swizzled LDS).
// A: [M x K] rows at m0..m0+127, B: [N x K] rows at n0..n0+127 (B^T; W is V x H).
template <bool F32SRC>
__device__ __forceinline__ void ktile(const void* A, const void* B,
                                      float4_t (&acc)[4][4],
                                      unsigned short* As, unsigned short* Bs,
                                      int m0, int n0) {
  const int tid = threadIdx.x;
  const int lane = tid & 63;
  const int wave = tid >> 6;
  const int wm = wave >> 1, wn = wave & 1;
  const int r0 = tid >> 2, c0 = tid & 3;  // staging: row, 16B-chunk slot
  const int cg = c0 ^ swz(r0);            // swizzled global chunk for this slot
  const int row16 = lane & 15, kq = lane >> 4;
  const int kqs = kq ^ swz(row16);        // swizzled chunk slot for fragment read
  const int aoff = (wm * 64 + row16) * BK + kqs * 8;
  const int boff = (wn * 64 + row16) * BK + kqs * 8;
  const int lds0 = __builtin_amdgcn_readfirstlane(wave * 1024);
  const int lds1 = __builtin_amdgcn_readfirstlane(4096 + wave * 1024);

  const unsigned short* Ab = nullptr; const unsigned short* Bb = nullptr;
  const float* Af = nullptr; const float* Bf = nullptr;
  if constexpr (!F32SRC) {
    Ab = (const unsigned short*)A + (size_t)(m0 + r0) * HD + cg * 8;
    Bb = (const unsigned short*)B + (size_t)(n0 + r0) * HD + cg * 8;
  } else {
    Af = (const float*)A + (size_t)(m0 + r0) * HD + cg * 8;
    Bf = (const float*)B + (size_t)(n0 + r0) * HD + cg * 8;
  }

  for (int kb = 0; kb < HD / BK; ++kb) {
    const int ke = kb * BK;
    if constexpr (!F32SRC) {
      async_copy16(Ab + ke, (char*)As + lds0);
      async_copy16(Ab + (size_t)64 * HD + ke, (char*)As + lds1);
      async_copy16(Bb + ke, (char*)Bs + lds0);
      async_copy16(Bb + (size_t)64 * HD + ke, (char*)Bs + lds1);
    } else {
      short8_t hA0 = pack8(*(const float4_t*)(Af + ke), *(const float4_t*)(Af + ke + 4));
      short8_t hA1 = pack8(*(const float4_t*)(Af + (size_t)64 * HD + ke),
                           *(const float4_t*)(Af + (size_t)64 * HD + ke + 4));
      short8_t hB0 = pack8(*(const float4_t*)(Bf + ke), *(const float4_t*)(Bf + ke + 4));
      short8_t hB1 = pack8(*(const float4_t*)(Bf + (size_t)64 * HD + ke),
                           *(const float4_t*)(Bf + (size_t)64 * HD + ke + 4));
      *(short8_t*)((char*)As + tid * 16) = hA0;
      *(short8_t*)((char*)As + 4096 + tid * 16) = hA1;
      *(short8_t*)((char*)Bs + tid * 16) = hB0;
      *(short8_t*)((char*)Bs + 4096 + tid * 16) = hB1;
    }
    __syncthreads();
    short8_t af[4], bf[4];
#pragma unroll
    for (int mi = 0; mi < 4; ++mi) af[mi] = *(const short8_t*)(As + aoff + mi * 16 * BK);
#pragma unroll
    for (int ni = 0; ni < 4; ++ni) bf[ni] = *(const short8_t*)(Bs + boff + ni * 16 * BK);
#pragma unroll
    for (int mi = 0; mi < 4; ++mi)
#pragma unroll
      for (int ni = 0; ni < 4; ++ni)
        acc[mi][ni] = __builtin_amdgcn_mfma_f32_16x16x32_bf16(af[mi], bf[ni], acc[mi][ni], 0, 0, 0);
    __syncthreads();
  }
}

// Pass 1: GEMM; optionally store bf16 logits; accumulate per-row sum(exp(z)).
// grid: (M/BM, V/BN, 2) -- z selects (student, teacher).
template <bool F32SRC, bool STORE>
__global__ __launch_bounds__(256, 2) void gemm_pass1(
    const void* A0, const void* A1, const void* B0, const void* B1,
    float* __restrict__ rowsum, unsigned short* __restrict__ store) {
  __shared__ __align__(16) unsigned short As[BM * BK];
  __shared__ __align__(16) unsigned short Bs[BN * BK];
  const int m0 = blockIdx.x * BM;
  const int n0 = blockIdx.y * BN;
  const int z = blockIdx.z;
  const void* A = z ? A1 : A0;
  const void* B = z ? B1 : B0;
  float4_t acc[4][4] = {};
  ktile<F32SRC>(A, B, acc, As, Bs, m0, n0);

  const int tid = threadIdx.x;
  const int lane = tid & 63;
  const int wave = tid >> 6;
  const int wm = wave >> 1, wn = wave & 1;
  const int row16 = lane & 15, kq = lane >> 4;

  if constexpr (STORE) {
    unsigned short* st = store + (size_t)z * BT * VD;
#pragma unroll
    for (int mi = 0; mi < 4; ++mi)
#pragma unroll
      for (int r = 0; r < 4; ++r) {
        const size_t grow = (size_t)(m0 + wm * 64 + mi * 16 + kq * 4 + r);
        const size_t gc0 = (size_t)(n0 + wn * 64 + row16);
#pragma unroll
        for (int ni = 0; ni < 4; ++ni)
          st[grow * VD + gc0 + ni * 16] = f2bf(acc[mi][ni][r]);
      }
  }

  float* rs = rowsum + z * BT;
#pragma unroll
  for (int mi = 0; mi < 4; ++mi)
#pragma unroll
    for (int r = 0; r < 4; ++r) {
      float s = __expf(acc[mi][0][r]) + __expf(acc[mi][1][r]) +
                __expf(acc[mi][2][r]) + __expf(acc[mi][3][r]);
      s += __shfl_xor(s, 1);
      s += __shfl_xor(s, 2);
      s += __shfl_xor(s, 4);
      s += __shfl_xor(s, 8);
      if (row16 == 0) atomicAdd(&rs[m0 + wm * 64 + mi * 16 + kq * 4 + r], s);
    }
}

// stats[i] = log(sum_exp) -> LSE; thread 0 seeds out with +ln2 (plain store,
// ordered before pass-2 atomics on the same stream).
__global__ __launch_bounds__(256) void lse_fix(float* __restrict__ stats,
                                               float* __restrict__ out) {
  const int i = blockIdx.x * 256 + threadIdx.x;
  if (i < 2 * BT) stats[i] = __logf(stats[i]);
  if (i == 0) out[0] = 0.6931471805599453f;
}

// Pass 2 (materialized path): JSD terms from stored bf16 logits; one block/row.
__global__ __launch_bounds__(256) void loss_from_blogits(
    const ushort8_t* __restrict__ zs, const ushort8_t* __restrict__ zt,
    const float* __restrict__ lse, float* __restrict__ out) {
  const int row = blockIdx.x;
  const float es = lse[row], et = lse[BT + row];
  const ushort8_t* ps = zs + (size_t)row * (VD / 8);
  const ushort8_t* pt = zt + (size_t)row * (VD / 8);
  float local = 0.f;
  for (int i = threadIdx.x; i < VD / 8; i += 256) {
    const ushort8_t a = ps[i], b = pt[i];
#pragma unroll
    for (int c = 0; c < 8; ++c) {
      const float ls = bf2f(a[c]) - es, lt = bf2f(b[c]) - et;
      const float p = __expf(ls), q = __expf(lt);
      local += p * ls + q * lt - (p + q) * __logf(p + q);
    }
  }
  local += __shfl_xor(local, 1);
  local += __shfl_xor(local, 2);
  local += __shfl_xor(local, 4);
  local += __shfl_xor(local, 8);
  local += __shfl_xor(local, 16);
  local += __shfl_xor(local, 32);
  __shared__ float red[4];
  const int lane = threadIdx.x & 63, wave = threadIdx.x >> 6;
  if (lane == 0) red[wave] = local;
  __syncthreads();
  if (threadIdx.x == 0)
    atomicAdd(out, (red[0] + red[1] + red[2] + red[3]) * (0.5f / BT));
}

// Pass 2 (recompute fallback): both GEMM tiles then joint JSD terms.
template <bool F32SRC>
__global__ __launch_bounds__(256, 2) void gemm_loss(
    const void* Asg, const void* Bsg, const void* Atg, const void* Btg,
    const float* __restrict__ lse, float* __restrict__ out) {
  __shared__ __align__(16) unsigned short As[BM * BK];
  __shared__ __align__(16) unsigned short Bs[BN * BK];
  __shared__ float red[4];
  const int m0 = blockIdx.x * BM;
  const int n0 = blockIdx.y * BN;
  float4_t acc_s[4][4] = {};
  ktile<F32SRC>(Asg, Bsg, acc_s, As, Bs, m0, n0);
  float4_t acc_t[4][4] = {};
  ktile<F32SRC>(Atg, Btg, acc_t, As, Bs, m0, n0);

  const int tid = threadIdx.x;
  const int lane = tid & 63;
  const int wave = tid >> 6;
  const int wm = wave >> 1;
  const int kq = lane >> 4;

  float local = 0.f;
#pragma unroll
  for (int mi = 0; mi < 4; ++mi)
#pragma unroll
    for (int r = 0; r < 4; ++r) {
      const int grow = m0 + wm * 64 + mi * 16 + kq * 4 + r;
      const float es = lse[grow], et = lse[BT + grow];
#pragma unroll
      for (int ni = 0; ni < 4; ++ni) {
        const float ls = acc_s[mi][ni][r] - es;
        const float lt = acc_t[mi][ni][r] - et;
        const float p = __expf(ls), q = __expf(lt);
        local += p * ls + q * lt - (p + q) * __logf(p + q);
      }
    }
  local += __shfl_xor(local, 1);
  local += __shfl_xor(local, 2);
  local += __shfl_xor(local, 4);
  local += __shfl_xor(local, 8);
  local += __shfl_xor(local, 16);
  local += __shfl_xor(local, 32);
  if (lane == 0) red[wave] = local;
  __syncthreads();
  if (tid == 0) atomicAdd(out, (red[0] + red[1] + red[2] + red[3]) * (0.5f / BT));
}

extern "C" void kernel_launch(void* const* d_in, const int* in_sizes, int n_in,
                              void* d_out, int out_size, void* d_ws, size_t ws_size,
                              hipStream_t stream) {
  const float* Xs = (const float*)d_in[0];
  const float* Xt = (const float*)d_in[1];
  const float* Ws = (const float*)d_in[2];
  const float* Wt = (const float*)d_in[3];
  float* out = (float*)d_out;
  char* ws = (char*)d_ws;

  const size_t STATS_B = (size_t)2 * BT * sizeof(float);          // 32 KB
  const size_t XB = (size_t)BT * HD * 2;                          // bf16 X
  const size_t WB = (size_t)VD * HD * 2;                          // bf16 W
  const size_t LOGIT_B = (size_t)2 * BT * VD * 2;                 // bf16 logits (s+t)
  const size_t PRECAST_NEED = STATS_B + 2 * XB + 2 * WB;          // ~296 MB
  const size_t BEST_NEED = PRECAST_NEED + LOGIT_B;                // ~820 MB
  const size_t MID_NEED = STATS_B + LOGIT_B;                      // ~524 MB

  float* stats = (float*)ws;
  hipMemsetAsync(stats, 0, STATS_B, stream);

  const dim3 blk(256);
  const dim3 g1(BT / BM, VD / BN, 2);
  const dim3 g2(BT / BM, VD / BN, 1);
  const int XN4 = BT * HD / 4;
  const int WN4 = VD * HD / 4;

  if (ws_size >= BEST_NEED) {
    // precast bf16 + materialize bf16 logits (GEMM runs once, best path)
    unsigned short* bXs = (unsigned short*)(ws + STATS_B);
    unsigned short* bXt = bXs + (size_t)BT * HD;
    unsigned short* bWs = bXt + (size_t)BT * HD;
    unsigned short* bWt = bWs + (size_t)VD * HD;
    unsigned short* logits = (unsigned short*)(ws + PRECAST_NEED);
    cast_f32_to_bf16<<<dim3(512), blk, 0, stream>>>((const float4_t*)Xs, (short4_t*)bXs, XN4);
    cast_f32_to_bf16<<<dim3(512), blk, 0, stream>>>((const float4_t*)Xt, (short4_t*)bXt, XN4);
    cast_f32_to_bf16<<<dim3(2048), blk, 0, stream>>>((const float4_t*)Ws, (short4_t*)bWs, WN4);
    cast_f32_to_bf16<<<dim3(2048), blk, 0, stream>>>((const float4_t*)Wt, (short4_t*)bWt, WN4);
    gemm_pass1<false, true><<<g1, blk, 0, stream>>>(bXs, bXt, bWs, bWt, stats, logits);
    lse_fix<<<dim3(32), blk, 0, stream>>>(stats, out);
    loss_from_blogits<<<dim3(BT), blk, 0, stream>>>(
        (const ushort8_t*)logits,
        (const ushort8_t*)(logits + (size_t)BT * VD), stats, out);
  } else if (ws_size >= MID_NEED) {
    // no precast: stage f32->bf16 on the fly, materialize bf16 logits
    unsigned short* logits = (unsigned short*)(ws + STATS_B);
    gemm_pass1<true, true><<<g1, blk, 0, stream>>>(Xs, Xt, Ws, Wt, stats, logits);
    lse_fix<<<dim3(32), blk, 0, stream>>>(stats, out);
    loss_from_blogits<<<dim3(BT), blk, 0, stream>>>(
        (const ushort8_t*)logits,
        (const ushort8_t*)(logits + (size_t)BT * VD), stats, out);
  } else if (ws_size >= PRECAST_NEED) {
    // precast bf16, recompute logits in pass 2
    unsigned short* bXs = (unsigned short*)(ws + STATS_B);
    unsigned short* bXt = bXs + (size_t)BT * HD;
    unsigned short* bWs = bXt + (size_t)BT * HD;
    unsigned short* bWt = bWs + (size_t)VD * HD;
    cast_f32_to_bf16<<<dim3(512), blk, 0, stream>>>((const float4_t*)Xs, (short4_t*)bXs, XN4);
    cast_f32_to_bf16<<<dim3(512), blk, 0, stream>>>((const float4_t*)Xt, (short4_t*)bXt, XN4);
    cast_f32_to_bf16<<<dim3(2048), blk, 0, stream>>>((const float4_t*)Ws, (short4_t*)bWs, WN4);
    cast_f32_to_bf16<<<dim3(2048), blk, 0, stream>>>((const float4_t*)Wt, (short4_t*)bWt, WN4);
    gemm_pass1<false, false><<<g1, blk, 0, stream>>>(bXs, bXt, bWs, bWt, stats, nullptr);
    lse_fix<<<dim3(32), blk, 0, stream>>>(stats, out);
    gemm_loss<false><<<g2, blk, 0, stream>>>(bXs, bWs, bXt, bWt, stats, out);
  } else {
    // minimal-ws fallback: everything on the fly (needs only 32 KB)
    gemm_pass1<true, false><<<g1, blk, 0, stream>>>(Xs, Xt, Ws, Wt, stats, nullptr);
    lse_fix<<<dim3(32), blk, 0, stream>>>(stats, out);
    gemm_loss<true><<<g2, blk, 0, stream>>>(Xs, Ws, Xt, Wt, stats, out);
  }
  (void)in_sizes; (void)n_in; (void)out_size;
}